// Round 1
// baseline (716.613 us; speedup 1.0000x reference)
//
#include <hip/hip_runtime.h>

#define LN_EPS 1e-5f

typedef __bf16 bf16x8 __attribute__((ext_vector_type(8)));
typedef float f32x4 __attribute__((ext_vector_type(4)));

__device__ __forceinline__ float b2f(unsigned short s) {
    union { unsigned u; float f; } c; c.u = ((unsigned)s) << 16; return c.f;
}
__device__ __forceinline__ unsigned short f2b(float f) {
    union { float f; unsigned u; } c; c.f = f;
    unsigned r = (c.u + 0x7FFFu + ((c.u >> 16) & 1u)) >> 16;
    return (unsigned short)r;
}
__device__ __forceinline__ float leaky(float x) { return x >= 0.f ? x : 0.01f * x; }

// ---------------- CSR build ----------------

__global__ void init_kernel(float* deg, int* fill, int n) {
    int i = blockIdx.x * 256 + threadIdx.x;
    if (i < n) { deg[i] = 1.0f; fill[i] = 0; }
}

__global__ void deg_kernel(const int* __restrict__ dst, float* deg, int e) {
    int i = blockIdx.x * 256 + threadIdx.x;
    if (i < e) atomicAdd(&deg[dst[i]], 1.0f);
}

// exclusive prefix sum of (deg-1) over n entries -> ptr[0..n]
__global__ void scan_kernel(const float* __restrict__ deg, int* __restrict__ ptr, int n) {
    __shared__ int wsum[16];
    int tid = threadIdx.x, lane = tid & 63, wid = tid >> 6;
    int carry = 0;
    for (int base = 0; base < n; base += 1024) {
        int i = base + tid;
        int v = (i < n) ? ((int)deg[i] - 1) : 0;
        int x = v;
        #pragma unroll
        for (int off = 1; off < 64; off <<= 1) {
            int y = __shfl_up(x, off, 64);
            if (lane >= off) x += y;
        }
        if (lane == 63) wsum[wid] = x;
        __syncthreads();
        int wexcl = 0, tot = 0;
        #pragma unroll
        for (int w = 0; w < 16; ++w) { int s = wsum[w]; tot += s; if (w < wid) wexcl += s; }
        if (i < n) ptr[i] = carry + wexcl + (x - v);
        carry += tot;
        __syncthreads();
    }
    if (tid == 0) ptr[n] = carry;
}

__global__ void dinv_kernel(float* deg, int n) {
    int i = blockIdx.x * 256 + threadIdx.x;
    if (i < n) deg[i] = rsqrtf(deg[i]);   // deg >= 1 always (self loop)
}

__global__ void fill_kernel(const int* __restrict__ src, const int* __restrict__ dst,
                            const float* __restrict__ dinv, const int* __restrict__ ptr,
                            int* fill, int* __restrict__ csrc, float* __restrict__ cw, int e) {
    int i = blockIdx.x * 256 + threadIdx.x;
    if (i < e) {
        int d = dst[i], s = src[i];
        int pos = atomicAdd(&fill[d], 1);
        int idx = ptr[d] + pos;
        csrc[idx] = s;
        cw[idx] = dinv[s] * dinv[d];
    }
}

// ---------------- weights: W^T in bf16 ----------------

__global__ void wt_kernel(const float* __restrict__ W1, const float* __restrict__ W2,
                          const float* __restrict__ W3, unsigned short* __restrict__ wt) {
    int k = blockIdx.x, l = blockIdx.y, nn = threadIdx.x;
    const float* W = (l == 0) ? W1 : (l == 1) ? W2 : W3;
    wt[l * 65536 + nn * 256 + k] = f2b(W[k * 256 + nn]);
}

// ---------------- layer 0: aggregate x (3 feats) then tiny matmul ----------------

__global__ void aggx_kernel(const float* __restrict__ x, const float* __restrict__ dinv,
                            const int* __restrict__ ptr, const int* __restrict__ csrc,
                            const float* __restrict__ cw, float* __restrict__ aggx, int n) {
    int i = blockIdx.x * 256 + threadIdx.x;
    if (i >= n) return;
    float w = dinv[i] * dinv[i];
    float a0 = w * x[i * 3], a1 = w * x[i * 3 + 1], a2 = w * x[i * 3 + 2];
    int e0 = ptr[i], e1 = ptr[i + 1];
    for (int e = e0; e < e1; ++e) {
        int s = csrc[e]; float we = cw[e];
        a0 += we * x[s * 3]; a1 += we * x[s * 3 + 1]; a2 += we * x[s * 3 + 2];
    }
    aggx[i * 3] = a0; aggx[i * 3 + 1] = a1; aggx[i * 3 + 2] = a2;
}

__global__ void h0_kernel(const float* __restrict__ aggx, const float* __restrict__ W0,
                          const float* __restrict__ b0, float* __restrict__ h,
                          unsigned short* __restrict__ hb, int n) {
    int row = blockIdx.x, d = threadIdx.x;
    size_t o = (size_t)row * 256 + d;
    if (row < n) {
        float v = b0[d] + aggx[row * 3] * W0[d] + aggx[row * 3 + 1] * W0[256 + d]
                + aggx[row * 3 + 2] * W0[512 + d];
        h[o] = v;
        hb[o] = f2b(v);
    } else {
        hb[o] = 0;   // zero pad rows for GEMM (ws is re-poisoned every call)
    }
}

// ---------------- GEMM: hw_bf16 = h_bf16 @ W  (via Wt rows) ----------------

__global__ __launch_bounds__(256) void gemm_kernel(const unsigned short* __restrict__ A,
                                                   const unsigned short* __restrict__ Bt,
                                                   unsigned short* __restrict__ C) {
    const int K = 256;
    int wid = threadIdx.x >> 6, lane = threadIdx.x & 63;
    int m0 = blockIdx.x * 64;
    int n0 = wid * 64;
    int lr = lane & 15, lg = lane >> 4;
    f32x4 acc[4][4];
    #pragma unroll
    for (int i = 0; i < 4; i++)
        #pragma unroll
        for (int j = 0; j < 4; j++) acc[i][j] = (f32x4)(0.f);
    const unsigned short* Ap = A + (size_t)(m0 + lr) * K + lg * 8;
    const unsigned short* Bp = Bt + (size_t)(n0 + lr) * K + lg * 8;
    for (int kk = 0; kk < K; kk += 32) {
        bf16x8 af[4], bfr[4];
        #pragma unroll
        for (int mi = 0; mi < 4; mi++) {
            af[mi]  = *(const bf16x8*)(Ap + (size_t)mi * 16 * K + kk);
            bfr[mi] = *(const bf16x8*)(Bp + (size_t)mi * 16 * K + kk);
        }
        #pragma unroll
        for (int mi = 0; mi < 4; mi++)
            #pragma unroll
            for (int ni = 0; ni < 4; ni++)
                acc[mi][ni] = __builtin_amdgcn_mfma_f32_16x16x32_bf16(af[mi], bfr[ni], acc[mi][ni], 0, 0, 0);
    }
    #pragma unroll
    for (int mi = 0; mi < 4; mi++)
        #pragma unroll
        for (int ni = 0; ni < 4; ni++)
            #pragma unroll
            for (int j = 0; j < 4; j++) {
                int r = m0 + mi * 16 + lg * 4 + j;
                int c = n0 + ni * 16 + lr;
                C[(size_t)r * 256 + c] = f2b(acc[mi][ni][j]);
            }
}

// ---------------- SpMM gather + bias + leaky + residual ----------------

__global__ __launch_bounds__(256) void spmm_kernel(const unsigned short* __restrict__ hw,
                                                   const int* __restrict__ ptr,
                                                   const int* __restrict__ csrc,
                                                   const float* __restrict__ cw,
                                                   const float* __restrict__ dinv,
                                                   const float* __restrict__ bias,
                                                   float* __restrict__ h,
                                                   unsigned short* __restrict__ hb, int n) {
    int wid = threadIdx.x >> 6, lane = threadIdx.x & 63;
    int node = blockIdx.x * 4 + wid;
    if (node >= n) return;
    int f0 = lane * 4;
    float sw = dinv[node]; sw = sw * sw;
    ushort4 v = *(const ushort4*)(hw + (size_t)node * 256 + f0);
    float a0 = sw * b2f(v.x), a1 = sw * b2f(v.y), a2 = sw * b2f(v.z), a3 = sw * b2f(v.w);
    int e0 = ptr[node], e1 = ptr[node + 1];
    for (int e = e0; e < e1; ++e) {
        int s = csrc[e]; float w = cw[e];
        ushort4 u = *(const ushort4*)(hw + (size_t)s * 256 + f0);
        a0 += w * b2f(u.x); a1 += w * b2f(u.y); a2 += w * b2f(u.z); a3 += w * b2f(u.w);
    }
    float4 bb = *(const float4*)(bias + f0);
    float4 hh = *(const float4*)(h + (size_t)node * 256 + f0);
    float r0 = leaky(a0 + bb.x) + hh.x;
    float r1 = leaky(a1 + bb.y) + hh.y;
    float r2 = leaky(a2 + bb.z) + hh.z;
    float r3 = leaky(a3 + bb.w) + hh.w;
    *(float4*)(h + (size_t)node * 256 + f0) = make_float4(r0, r1, r2, r3);
    ushort4 o; o.x = f2b(r0); o.y = f2b(r1); o.z = f2b(r2); o.w = f2b(r3);
    *(ushort4*)(hb + (size_t)node * 256 + f0) = o;
}

// ---------------- segment max pooling ----------------

__global__ __launch_bounds__(256) void pool_kernel(const float* __restrict__ h,
                                                   const int* __restrict__ batch,
                                                   float* __restrict__ pooled, int n) {
    int b = blockIdx.x, d = threadIdx.x;
    int lo = 0, hi = n;
    while (lo < hi) { int m = (lo + hi) >> 1; if (batch[m] < b) lo = m + 1; else hi = m; }
    int s = lo;
    lo = 0; hi = n;
    while (lo < hi) { int m = (lo + hi) >> 1; if (batch[m] < b + 1) lo = m + 1; else hi = m; }
    int e = lo;
    float mx = -3.402823466e38f;
    for (int r = s; r < e; ++r) mx = fmaxf(mx, h[(size_t)r * 256 + d]);
    pooled[(size_t)b * 256 + d] = mx;
}

// ---------------- head: V=LN(pooled); action MLP; z; out ----------------

__device__ __forceinline__ float blk_sum(float v, float* red) {
    #pragma unroll
    for (int off = 32; off; off >>= 1) v += __shfl_down(v, off, 64);
    int lane = threadIdx.x & 63, wid = threadIdx.x >> 6;
    if (lane == 0) red[wid] = v;
    __syncthreads();
    float s = red[0] + red[1] + red[2] + red[3];
    __syncthreads();
    return s;
}

__global__ __launch_bounds__(256) void head_kernel(
    const float* __restrict__ pooled, const float* __restrict__ a,
    const float* __restrict__ afc1_w, const float* __restrict__ afc1_b,
    const float* __restrict__ afc2_w, const float* __restrict__ afc2_b,
    const float* __restrict__ afc3_w, const float* __restrict__ afc3_b,
    const float* __restrict__ fc1_w, const float* __restrict__ fc1_b,
    const float* __restrict__ fc2_w, const float* __restrict__ fc2_b,
    const float* __restrict__ ln1_g, const float* __restrict__ ln1_b,
    const float* __restrict__ ln2_g, const float* __restrict__ ln2_b,
    const float* __restrict__ ln4_g, const float* __restrict__ ln4_b,
    const float* __restrict__ ln5_g, const float* __restrict__ ln5_b,
    float* __restrict__ out) {
    __shared__ float red[4];
    __shared__ float sM[2];
    __shared__ float s1[56], s2[56], sZ[256], sT[64];
    int b = blockIdx.x, tid = threadIdx.x;

    // V = LN(pooled[b], ln2)
    float pv = pooled[(size_t)b * 256 + tid];
    float m = blk_sum(pv, red) * (1.f / 256.f);
    float d0 = pv - m;
    float var = blk_sum(d0 * d0, red) * (1.f / 256.f);
    float V = d0 * rsqrtf(var + LN_EPS) * ln2_g[tid] + ln2_b[tid];

    // t1 = leaky(a @ afc1 + b)  [56]
    if (tid < 56) {
        float acc = afc1_b[tid];
        #pragma unroll
        for (int k = 0; k < 7; ++k) acc += a[b * 7 + k] * afc1_w[k * 56 + tid];
        s1[tid] = leaky(acc);
    }
    __syncthreads();
    // LN5 over 56
    if (tid == 0) {
        float s = 0.f; for (int k = 0; k < 56; ++k) s += s1[k];
        float mm = s / 56.f;
        float q = 0.f; for (int k = 0; k < 56; ++k) { float d = s1[k] - mm; q += d * d; }
        sM[0] = mm; sM[1] = rsqrtf(q / 56.f + LN_EPS);
    }
    __syncthreads();
    if (tid < 56) s1[tid] = (s1[tid] - sM[0]) * sM[1] * ln5_g[tid] + ln5_b[tid];
    __syncthreads();
    // t2 = leaky(t1 @ afc2 + b)  [56]
    if (tid < 56) {
        float acc = afc2_b[tid];
        for (int k = 0; k < 56; ++k) acc += s1[k] * afc2_w[k * 56 + tid];
        s2[tid] = leaky(acc);
    }
    __syncthreads();
    // av = LN1(leaky(t2 @ afc3 + b))  [256]
    float acc = afc3_b[tid];
    for (int k = 0; k < 56; ++k) acc += s2[k] * afc3_w[k * 256 + tid];
    acc = leaky(acc);
    m = blk_sum(acc, red) * (1.f / 256.f);
    d0 = acc - m;
    var = blk_sum(d0 * d0, red) * (1.f / 256.f);
    float av = d0 * rsqrtf(var + LN_EPS) * ln1_g[tid] + ln1_b[tid];

    float z = V * av;
    sZ[tid] = z;
    __syncthreads();
    // zz = leaky(z @ fc1 + b)  [64]
    if (tid < 64) {
        float a2 = fc1_b[tid];
        for (int k = 0; k < 256; ++k) a2 += sZ[k] * fc1_w[k * 64 + tid];
        sT[tid] = leaky(a2);
    }
    __syncthreads();
    // LN4 over 64 + final dot
    if (tid == 0) {
        float s = 0.f; for (int k = 0; k < 64; ++k) s += sT[k];
        float mm = s / 64.f;
        float q = 0.f; for (int k = 0; k < 64; ++k) { float d = sT[k] - mm; q += d * d; }
        float r = rsqrtf(q / 64.f + LN_EPS);
        float o = fc2_b[0];
        for (int k = 0; k < 64; ++k) {
            float zz = (sT[k] - mm) * r * ln4_g[k] + ln4_b[k];
            o += zz * fc2_w[k];
        }
        out[b] = o;
    }
}

// ---------------- launch ----------------

extern "C" void kernel_launch(void* const* d_in, const int* in_sizes, int n_in,
                              void* d_out, int out_size, void* d_ws, size_t ws_size,
                              hipStream_t stream) {
    const float* x     = (const float*)d_in[0];
    const int*   eidx  = (const int*)d_in[1];
    const int*   batch = (const int*)d_in[2];
    const float* a     = (const float*)d_in[3];
    const float* W0 = (const float*)d_in[4];  const float* b0 = (const float*)d_in[5];
    const float* W1 = (const float*)d_in[6];  const float* b1 = (const float*)d_in[7];
    const float* W2 = (const float*)d_in[8];  const float* b2 = (const float*)d_in[9];
    const float* W3 = (const float*)d_in[10]; const float* b3 = (const float*)d_in[11];
    const float* afc1_w = (const float*)d_in[12]; const float* afc1_b = (const float*)d_in[13];
    const float* afc2_w = (const float*)d_in[14]; const float* afc2_b = (const float*)d_in[15];
    const float* afc3_w = (const float*)d_in[16]; const float* afc3_b = (const float*)d_in[17];
    const float* fc1_w  = (const float*)d_in[18]; const float* fc1_b  = (const float*)d_in[19];
    const float* fc2_w  = (const float*)d_in[20]; const float* fc2_b  = (const float*)d_in[21];
    const float* ln1_g = (const float*)d_in[22]; const float* ln1_b = (const float*)d_in[23];
    const float* ln2_g = (const float*)d_in[24]; const float* ln2_b = (const float*)d_in[25];
    const float* ln4_g = (const float*)d_in[26]; const float* ln4_b = (const float*)d_in[27];
    const float* ln5_g = (const float*)d_in[28]; const float* ln5_b = (const float*)d_in[29];

    int N = in_sizes[0] / 3;
    int E = in_sizes[1] / 2;
    int B = in_sizes[3] / 7;
    int Mpad = ((N + 63) / 64) * 64;

    char* p = (char*)d_ws;
    auto alloc = [&](size_t bytes) -> char* {
        char* r = p; p += (bytes + 255) & ~(size_t)255; return r;
    };
    float* deg  = (float*)alloc((size_t)N * 4);          // becomes dinv in-place
    int*   fill = (int*)alloc((size_t)N * 4);
    int*   ptr  = (int*)alloc((size_t)(N + 1) * 4);
    int*   csrc = (int*)alloc((size_t)E * 4);
    float* cw   = (float*)alloc((size_t)E * 4);
    float* aggx = (float*)alloc((size_t)N * 3 * 4);
    float* h    = (float*)alloc((size_t)N * 256 * 4);
    unsigned short* hb  = (unsigned short*)alloc((size_t)Mpad * 256 * 2);
    unsigned short* hwb = (unsigned short*)alloc((size_t)Mpad * 256 * 2);
    unsigned short* wt  = (unsigned short*)alloc((size_t)3 * 256 * 256 * 2);
    float* pooled = (float*)alloc((size_t)B * 256 * 4);

    const int* srcl = eidx;
    const int* dstl = eidx + E;

    init_kernel<<<(N + 255) / 256, 256, 0, stream>>>(deg, fill, N);
    deg_kernel<<<(E + 255) / 256, 256, 0, stream>>>(dstl, deg, E);
    scan_kernel<<<1, 1024, 0, stream>>>(deg, ptr, N);
    dinv_kernel<<<(N + 255) / 256, 256, 0, stream>>>(deg, N);
    fill_kernel<<<(E + 255) / 256, 256, 0, stream>>>(srcl, dstl, deg, ptr, fill, csrc, cw, E);
    wt_kernel<<<dim3(256, 3), 256, 0, stream>>>(W1, W2, W3, wt);
    aggx_kernel<<<(N + 255) / 256, 256, 0, stream>>>(x, deg, ptr, csrc, cw, aggx, N);
    h0_kernel<<<Mpad, 256, 0, stream>>>(aggx, W0, b0, h, hb, N);

    const float* biases[3] = { b1, b2, b3 };
    for (int l = 0; l < 3; ++l) {
        gemm_kernel<<<Mpad / 64, 256, 0, stream>>>(hb, wt + (size_t)l * 65536, hwb);
        spmm_kernel<<<(N + 3) / 4, 256, 0, stream>>>(hwb, ptr, csrc, cw, deg, biases[l], h, hb, N);
    }

    pool_kernel<<<B, 256, 0, stream>>>(h, batch, pooled, N);
    head_kernel<<<B, 256, 0, stream>>>(pooled, a,
        afc1_w, afc1_b, afc2_w, afc2_b, afc3_w, afc3_b,
        fc1_w, fc1_b, fc2_w, fc2_b,
        ln1_g, ln1_b, ln2_g, ln2_b, ln4_g, ln4_b, ln5_g, ln5_b,
        (float*)d_out);
}